// Round 1
// baseline (380.340 us; speedup 1.0000x reference)
//
#include <hip/hip_runtime.h>

#define NPTS  32768
#define DIM   256
#define KCB   1024
#define BM    64
#define BK    64
#define DT    32

#define ZQ_OFF   0
#define LOSS_OFF 8388608
#define IDX_OFF  8388609

// z layout [B, D, H, W]: point n = b*1024 + h*32 + w ; element (n, d) at
// b*262144 + d*1024 + hw
__device__ __forceinline__ int z_base(int n) {
    return ((n >> 10) << 18) | (n & 1023);
}

// numpy pairwise sum (AVX512 npyv path) of squares of 128 elements (stride in
// elements). r_j[l] = sq[16j+l]; S = ((r0+r1)+(r2+r3))+((r4+r5)+(r6+r7));
// horizontal tree at distances 8,4,2,1 (gcc _mm512_reduce_add_ps order).
__device__ __forceinline__ float np_half_sq(const float* __restrict__ p, int stride) {
    float S[16];
#pragma unroll
    for (int l = 0; l < 16; ++l) {
        float t[8];
#pragma unroll
        for (int j = 0; j < 8; ++j) {
            float v = p[(j * 16 + l) * stride];
            t[j] = __fmul_rn(v, v);          // numpy rounds z**2 before summing
        }
        S[l] = __fadd_rn(__fadd_rn(__fadd_rn(t[0], t[1]), __fadd_rn(t[2], t[3])),
                         __fadd_rn(__fadd_rn(t[4], t[5]), __fadd_rn(t[6], t[7])));
    }
    float u[8];
#pragma unroll
    for (int i = 0; i < 8; ++i) u[i] = __fadd_rn(S[i], S[i + 8]);
    float v4[4];
#pragma unroll
    for (int i = 0; i < 4; ++i) v4[i] = __fadd_rn(u[i], u[i + 4]);
    float w0 = __fadd_rn(v4[0], v4[2]);
    float w1 = __fadd_rn(v4[1], v4[3]);
    return __fadd_rn(w0, w1);
}

// numpy pairwise_sum for n=256 (> PW_BLOCKSIZE=128): half(0:128) + half(128:256)
__device__ __forceinline__ float np_sum256_sq(const float* __restrict__ p, int stride) {
    float h0 = np_half_sq(p, stride);
    float h1 = np_half_sq(p + 128 * stride, stride);
    return __fadd_rn(h0, h1);
}

__global__ __launch_bounds__(256) void e2_kernel(const float* __restrict__ emb,
                                                 float* __restrict__ e2) {
    int k = blockIdx.x * 256 + threadIdx.x;
    if (k < KCB) e2[k] = np_sum256_sq(emb + k * DIM, 1);
}

__global__ __launch_bounds__(256) void z2_kernel(const float* __restrict__ z,
                                                 float* __restrict__ z2) {
    int n = blockIdx.x * 256 + threadIdx.x;
    if (n < NPTS) z2[n] = np_sum256_sq(z + z_base(n), 1024);
}

// Fused distance GEMM + per-row argmin. dot accumulated as ONE in-order fma
// chain over d=0..255 per (point, k) to mirror BLAS sgemm's sequential K loop.
__global__ __launch_bounds__(256) void dist_argmin_kernel(
    const float* __restrict__ z, const float* __restrict__ emb,
    const float* __restrict__ z2w, const float* __restrict__ e2w,
    int* __restrict__ bestk, float* __restrict__ out_idx)
{
    __shared__ float zs[DT][BM];        // [dd][p]
    __shared__ float es[DT][68];        // [dd][kk], pad 68 keeps b128 16B-aligned
    __shared__ float redv[BM][16];
    __shared__ int   redi[BM][16];

    const int tid = threadIdx.x;
    const int tx = tid & 15;            // codeword group within tile
    const int ty = tid >> 4;            // point group (0..15)
    const int n0 = blockIdx.x * BM;

    float z2r[4];
#pragma unroll
    for (int r = 0; r < 4; ++r) z2r[r] = z2w[n0 + 4 * ty + r];

    float bv[4];
    int   bi[4];
#pragma unroll
    for (int r = 0; r < 4; ++r) { bv[r] = __builtin_huge_valf(); bi[r] = 0; }

    // staging index precompute
    const int sp  = tid & 63;           // point for z staging
    const int sd0 = tid >> 6;           // base dd for z staging (0..3)
    const int zb  = z_base(n0 + sp);
    const int edd = tid & 31;           // dd for e staging
    const int ekb = tid >> 5;           // base kk for e staging (0..7)

    for (int kt = 0; kt < KCB / BK; ++kt) {
        const int k0 = kt * BK;
        float acc[4][4] = {};
        for (int dt = 0; dt < DIM / DT; ++dt) {
            __syncthreads();            // previous tile fully consumed
            const int dbase = dt * DT;
#pragma unroll
            for (int rr = 0; rr < 8; ++rr) {
                int dd = sd0 + rr * 4;
                zs[dd][sp] = z[zb + ((dbase + dd) << 10)];
            }
#pragma unroll
            for (int rr = 0; rr < 8; ++rr) {
                int kk = ekb + rr * 8;
                es[edd][kk] = emb[(k0 + kk) * DIM + dbase + edd];
            }
            __syncthreads();
#pragma unroll
            for (int dd = 0; dd < DT; ++dd) {
                float4 za = *(const float4*)&zs[dd][4 * ty];
                float4 eb = *(const float4*)&es[dd][4 * tx];
                acc[0][0] = __builtin_fmaf(za.x, eb.x, acc[0][0]);
                acc[0][1] = __builtin_fmaf(za.x, eb.y, acc[0][1]);
                acc[0][2] = __builtin_fmaf(za.x, eb.z, acc[0][2]);
                acc[0][3] = __builtin_fmaf(za.x, eb.w, acc[0][3]);
                acc[1][0] = __builtin_fmaf(za.y, eb.x, acc[1][0]);
                acc[1][1] = __builtin_fmaf(za.y, eb.y, acc[1][1]);
                acc[1][2] = __builtin_fmaf(za.y, eb.z, acc[1][2]);
                acc[1][3] = __builtin_fmaf(za.y, eb.w, acc[1][3]);
                acc[2][0] = __builtin_fmaf(za.z, eb.x, acc[2][0]);
                acc[2][1] = __builtin_fmaf(za.z, eb.y, acc[2][1]);
                acc[2][2] = __builtin_fmaf(za.z, eb.z, acc[2][2]);
                acc[2][3] = __builtin_fmaf(za.z, eb.w, acc[2][3]);
                acc[3][0] = __builtin_fmaf(za.w, eb.x, acc[3][0]);
                acc[3][1] = __builtin_fmaf(za.w, eb.y, acc[3][1]);
                acc[3][2] = __builtin_fmaf(za.w, eb.z, acc[3][2]);
                acc[3][3] = __builtin_fmaf(za.w, eb.w, acc[3][3]);
            }
        }
        // distances, exactly as ref: t1 = z2 + e2 ; d = t1 - 2*dot (2*dot exact)
#pragma unroll
        for (int c = 0; c < 4; ++c) {
            int k = k0 + 4 * tx + c;
            float e2v = e2w[k];
#pragma unroll
            for (int r = 0; r < 4; ++r) {
                float t1 = __fadd_rn(z2r[r], e2v);
                float dcur = __fsub_rn(t1, __fmul_rn(2.0f, acc[r][c]));
                if (dcur < bv[r]) { bv[r] = dcur; bi[r] = k; }  // strict <: first min wins
            }
        }
    }
#pragma unroll
    for (int r = 0; r < 4; ++r) {
        redv[4 * ty + r][tx] = bv[r];
        redi[4 * ty + r][tx] = bi[r];
    }
    __syncthreads();
    if (tid < BM) {
        float v = redv[tid][0];
        int   i = redi[tid][0];
#pragma unroll
        for (int t = 1; t < 16; ++t) {
            float v2 = redv[tid][t];
            int   i2 = redi[tid][t];
            if (v2 < v || (v2 == v && i2 < i)) { v = v2; i = i2; }  // np.argmin tie-break
        }
        bestk[n0 + tid] = i;
        out_idx[n0 + tid] = (float)i;
    }
}

__global__ __launch_bounds__(256) void zq_loss_kernel(
    const float* __restrict__ z, const float* __restrict__ emb,
    const int* __restrict__ bestk, float* __restrict__ zq,
    double* __restrict__ parts)
{
    const int n = blockIdx.x * 256 + threadIdx.x;
    const int kk = bestk[n];
    const float* er = emb + kk * DIM;
    const int zb = z_base(n);
    double s = 0.0;
#pragma unroll 8
    for (int d = 0; d < DIM; ++d) {
        float ev = er[d];
        float zv = z[zb + (d << 10)];
        zq[zb + (d << 10)] = ev;
        float df = ev - zv;
        s = fma((double)df, (double)df, s);
    }
    for (int off = 32; off; off >>= 1) s += __shfl_down(s, off, 64);
    __shared__ double sred[4];
    if ((threadIdx.x & 63) == 0) sred[threadIdx.x >> 6] = s;
    __syncthreads();
    if (threadIdx.x == 0)
        parts[blockIdx.x] = (sred[0] + sred[1]) + (sred[2] + sred[3]);
}

__global__ __launch_bounds__(128) void loss_final_kernel(
    const double* __restrict__ parts, float* __restrict__ out_loss)
{
    int t = threadIdx.x;                 // 128 threads
    double v = parts[t];
    for (int off = 32; off; off >>= 1) v += __shfl_down(v, off, 64);
    __shared__ double w2[2];
    if ((t & 63) == 0) w2[t >> 6] = v;
    __syncthreads();
    if (t == 0)
        out_loss[0] = (float)(1.25 * ((w2[0] + w2[1]) / 8388608.0));
}

extern "C" void kernel_launch(void* const* d_in, const int* in_sizes, int n_in,
                              void* d_out, int out_size, void* d_ws, size_t ws_size,
                              hipStream_t stream) {
    const float* z   = (const float*)d_in[0];
    const float* emb = (const float*)d_in[1];
    float* out = (float*)d_out;

    // workspace: z2[32768] f32 | e2[1024] f32 | bestk[32768] i32 | parts[128] f64
    float*  z2w   = (float*)d_ws;
    float*  e2w   = z2w + NPTS;
    int*    bestk = (int*)(e2w + KCB);
    double* parts = (double*)((char*)d_ws + 266240);  // 8-byte aligned

    e2_kernel<<<KCB / 256, 256, 0, stream>>>(emb, e2w);
    z2_kernel<<<NPTS / 256, 256, 0, stream>>>(z, z2w);
    dist_argmin_kernel<<<NPTS / BM, 256, 0, stream>>>(z, emb, z2w, e2w,
                                                      bestk, out + IDX_OFF);
    zq_loss_kernel<<<NPTS / 256, 256, 0, stream>>>(z, emb, bestk,
                                                   out + ZQ_OFF, parts);
    loss_final_kernel<<<1, 128, 0, stream>>>(parts, out + LOSS_OFF);
}

// Round 2
// 350.006 us; speedup vs baseline: 1.0867x; 1.0867x over previous
//
#include <hip/hip_runtime.h>

#define NPTS  32768
#define DIM   256
#define KCB   1024
#define BM    128
#define BK    128
#define DT    32
#define NSPLIT 4

#define ZQ_OFF   0
#define LOSS_OFF 8388608
#define IDX_OFF  8388609

// z layout [B, D, H, W]: point n = b*1024 + h*32 + w ; element (n, d) at
// b*262144 + d*1024 + hw
__device__ __forceinline__ int z_base(int n) {
    return ((n >> 10) << 18) | (n & 1023);
}

// ---- numpy pairwise sum (AVX512 npyv order) of squares, 128 elems ----
__device__ __forceinline__ float np_half_sq(const float* __restrict__ p, int stride) {
    float S[16];
#pragma unroll
    for (int l = 0; l < 16; ++l) {
        float t[8];
#pragma unroll
        for (int j = 0; j < 8; ++j) {
            float v = p[(j * 16 + l) * stride];
            t[j] = __fmul_rn(v, v);
        }
        S[l] = __fadd_rn(__fadd_rn(__fadd_rn(t[0], t[1]), __fadd_rn(t[2], t[3])),
                         __fadd_rn(__fadd_rn(t[4], t[5]), __fadd_rn(t[6], t[7])));
    }
    float u[8];
#pragma unroll
    for (int i = 0; i < 8; ++i) u[i] = __fadd_rn(S[i], S[i + 8]);
    float v4[4];
#pragma unroll
    for (int i = 0; i < 4; ++i) v4[i] = __fadd_rn(u[i], u[i + 4]);
    return __fadd_rn(__fadd_rn(v4[0], v4[2]), __fadd_rn(v4[1], v4[3]));
}

__device__ __forceinline__ float np_sum256_sq(const float* __restrict__ p, int stride) {
    return __fadd_rn(np_half_sq(p, stride), np_half_sq(p + 128 * stride, stride));
}

__global__ __launch_bounds__(256) void e2_kernel(const float* __restrict__ emb,
                                                 float* __restrict__ e2) {
    int k = blockIdx.x * 256 + threadIdx.x;
    if (k < KCB) e2[k] = np_sum256_sq(emb + k * DIM, 1);
}

__global__ __launch_bounds__(256) void z2_kernel(const float* __restrict__ z,
                                                 float* __restrict__ z2,
                                                 unsigned long long* __restrict__ cand) {
    int n = blockIdx.x * 256 + threadIdx.x;
    z2[n] = np_sum256_sq(z + z_base(n), 1024);
    cand[n] = 0x7FFFFFFFFFFFFFFFULL;   // init for atomicMin (re-poisoned each call)
}

__device__ __forceinline__ unsigned long long pack_vi(float v, int i) {
    unsigned int u = __float_as_uint(v);
    unsigned int key = (u & 0x80000000u) ? ~u : u;   // monotone float->uint (finite)
    return ((unsigned long long)key << 32) | (unsigned int)i;
}

// smem layout (floats): zs = [0 .. 4096) as [dd][128]; es = [4096 .. 4096+32*132)
// as [dd][132] (stride 132: 16B-aligned rows, 4-way-max staging writes).
// After compute, [0..2048) aliased as redv, [2048..4096) as redi.
#define SMEM_FLOATS (4096 + 32 * 132)

__global__ __launch_bounds__(256, 4) void dist_argmin_kernel(
    const float* __restrict__ z, const float* __restrict__ emb,
    const float* __restrict__ z2w, const float* __restrict__ e2w,
    unsigned long long* __restrict__ cand)
{
    __shared__ __align__(16) float smem[SMEM_FLOATS];
    float* zs = smem;            // [dd][128]
    float* es = smem + 4096;     // [dd][132]

    const int tid = threadIdx.x;
    const int tx = tid & 15;
    const int ty = tid >> 4;
    const int pt = blockIdx.x & 255;
    const int split = blockIdx.x >> 8;
    const int n0 = pt << 7;                 // 128 points per tile
    const int kbase = split << 8;           // 256 k per split

    const int zb = z_base(n0);

    float z2r[8];
#pragma unroll
    for (int i = 0; i < 8; ++i)
        z2r[i] = z2w[n0 + (i >> 2) * 64 + 4 * ty + (i & 3)];

    float bv[8];
    int   bi[8];
#pragma unroll
    for (int i = 0; i < 8; ++i) { bv[i] = __builtin_huge_valf(); bi[i] = 0; }

    // staging thread mapping
    const int sp2 = (tid & 63) * 2;         // point pair for z staging
    const int zd0 = tid >> 6;               // 0..3
    const int edd2 = (tid & 15) * 2;        // d pair for e staging
    const int ekb  = tid >> 4;              // 0..15

    for (int kt = 0; kt < 2; ++kt) {
        const int k0 = kbase + kt * BK;
        float acc[8][8];
#pragma unroll
        for (int i = 0; i < 8; ++i)
#pragma unroll
            for (int j = 0; j < 8; ++j) acc[i][j] = 0.0f;

        for (int dt = 0; dt < DIM / DT; ++dt) {
            const int dbase = dt * DT;
            __syncthreads();                // previous tile fully consumed
#pragma unroll
            for (int rr = 0; rr < 8; ++rr) {
                int dd = zd0 + 4 * rr;
                float2 v = *(const float2*)(z + zb + ((dbase + dd) << 10) + sp2);
                *(float2*)(zs + dd * 128 + sp2) = v;
            }
#pragma unroll
            for (int rr = 0; rr < 8; ++rr) {
                int kk = ekb + 16 * rr;
                float2 v = *(const float2*)(emb + (k0 + kk) * DIM + dbase + edd2);
                es[edd2 * 132 + kk] = v.x;
                es[(edd2 + 1) * 132 + kk] = v.y;
            }
            __syncthreads();
#pragma unroll
            for (int dd = 0; dd < DT; ++dd) {
                const float* zrow = zs + dd * 128;
                const float* erow = es + dd * 132;
                float4 za0 = *(const float4*)(zrow + 4 * ty);
                float4 za1 = *(const float4*)(zrow + 64 + 4 * ty);
                float4 eb0 = *(const float4*)(erow + 4 * tx);
                float4 eb1 = *(const float4*)(erow + 64 + 4 * tx);
                float zaf[8] = {za0.x, za0.y, za0.z, za0.w, za1.x, za1.y, za1.z, za1.w};
                float ebf[8] = {eb0.x, eb0.y, eb0.z, eb0.w, eb1.x, eb1.y, eb1.z, eb1.w};
#pragma unroll
                for (int i = 0; i < 8; ++i)
#pragma unroll
                    for (int j = 0; j < 8; ++j)
                        acc[i][j] = __builtin_fmaf(zaf[i], ebf[j], acc[i][j]);
            }
        }
        // distances exactly as ref: t1 = z2 + e2 ; d = t1 - 2*dot. k ascending.
#pragma unroll
        for (int j = 0; j < 8; ++j) {
            int k = k0 + (j >> 2) * 64 + 4 * tx + (j & 3);
            float e2v = e2w[k];
#pragma unroll
            for (int i = 0; i < 8; ++i) {
                float t1 = __fadd_rn(z2r[i], e2v);
                float dcur = __fsub_rn(t1, __fmul_rn(2.0f, acc[i][j]));
                if (dcur < bv[i]) { bv[i] = dcur; bi[i] = k; }   // strict <: first min
            }
        }
    }

    // block reduction over tx (16 threads per row), np tie-break
    __syncthreads();
    float* redv = smem;                     // [128][16]
    int*   redi = (int*)(smem + 2048);      // [128][16]
#pragma unroll
    for (int i = 0; i < 8; ++i) {
        int row = (i >> 2) * 64 + 4 * ty + (i & 3);
        redv[row * 16 + tx] = bv[i];
        redi[row * 16 + tx] = bi[i];
    }
    __syncthreads();
    if (tid < 128) {
        float v = redv[tid * 16];
        int   i = redi[tid * 16];
#pragma unroll
        for (int t = 1; t < 16; ++t) {
            float v2 = redv[tid * 16 + t];
            int   i2 = redi[tid * 16 + t];
            if (v2 < v || (v2 == v && i2 < i)) { v = v2; i = i2; }
        }
        atomicMin(&cand[n0 + tid], pack_vi(v, i));
    }
}

__global__ __launch_bounds__(256) void zq_loss_kernel(
    const float* __restrict__ z, const float* __restrict__ emb,
    const unsigned long long* __restrict__ cand, float* __restrict__ zq,
    float* __restrict__ out_idx, double* __restrict__ parts)
{
    const int n = blockIdx.x * 256 + threadIdx.x;
    const int kk = (int)(unsigned int)(cand[n] & 0xFFFFFFFFULL);
    out_idx[n] = (float)kk;
    const float* er = emb + kk * DIM;
    const int zb = z_base(n);
    double s = 0.0;
#pragma unroll 8
    for (int d = 0; d < DIM; ++d) {
        float ev = er[d];
        float zv = z[zb + (d << 10)];
        zq[zb + (d << 10)] = ev;
        float df = ev - zv;
        s = fma((double)df, (double)df, s);
    }
    for (int off = 32; off; off >>= 1) s += __shfl_down(s, off, 64);
    __shared__ double sred[4];
    if ((threadIdx.x & 63) == 0) sred[threadIdx.x >> 6] = s;
    __syncthreads();
    if (threadIdx.x == 0)
        parts[blockIdx.x] = (sred[0] + sred[1]) + (sred[2] + sred[3]);
}

__global__ __launch_bounds__(128) void loss_final_kernel(
    const double* __restrict__ parts, float* __restrict__ out_loss)
{
    int t = threadIdx.x;
    double v = parts[t];
    for (int off = 32; off; off >>= 1) v += __shfl_down(v, off, 64);
    __shared__ double w2[2];
    if ((t & 63) == 0) w2[t >> 6] = v;
    __syncthreads();
    if (t == 0)
        out_loss[0] = (float)(1.25 * ((w2[0] + w2[1]) / 8388608.0));
}

extern "C" void kernel_launch(void* const* d_in, const int* in_sizes, int n_in,
                              void* d_out, int out_size, void* d_ws, size_t ws_size,
                              hipStream_t stream) {
    const float* z   = (const float*)d_in[0];
    const float* emb = (const float*)d_in[1];
    float* out = (float*)d_out;

    // ws: z2[32768] f32 | e2[1024] f32 | cand[32768] u64 | parts[128] f64
    float* z2w = (float*)d_ws;
    float* e2w = z2w + NPTS;
    unsigned long long* cand = (unsigned long long*)((char*)d_ws + 135168);
    double* parts = (double*)((char*)d_ws + 135168 + NPTS * 8);

    e2_kernel<<<KCB / 256, 256, 0, stream>>>(emb, e2w);
    z2_kernel<<<NPTS / 256, 256, 0, stream>>>(z, z2w, cand);
    dist_argmin_kernel<<<(NPTS / BM) * NSPLIT, 256, 0, stream>>>(z, emb, z2w, e2w, cand);
    zq_loss_kernel<<<NPTS / 256, 256, 0, stream>>>(z, emb, cand, out + ZQ_OFF,
                                                   out + IDX_OFF, parts);
    loss_final_kernel<<<1, 128, 0, stream>>>(parts, out + LOSS_OFF);
}

// Round 3
// 320.313 us; speedup vs baseline: 1.1874x; 1.0927x over previous
//
#include <hip/hip_runtime.h>

#define NPTS  32768
#define DIM   256
#define KCB   1024
#define BM    128
#define BK    128
#define DT    32
#define NSPLIT 4

#define ZQ_OFF   0
#define LOSS_OFF 8388608
#define IDX_OFF  8388609

// z layout [B, D, H, W]: point n = b*1024 + h*32 + w ; element (n, d) at
// b*262144 + d*1024 + hw
__device__ __forceinline__ int z_base(int n) {
    return ((n >> 10) << 18) | (n & 1023);
}

// ---- numpy pairwise sum (AVX512 npyv order) of squares, 128 elems ----
__device__ __forceinline__ float np_half_sq(const float* __restrict__ p, int stride) {
    float S[16];
#pragma unroll
    for (int l = 0; l < 16; ++l) {
        float t[8];
#pragma unroll
        for (int j = 0; j < 8; ++j) {
            float v = p[(j * 16 + l) * stride];
            t[j] = __fmul_rn(v, v);
        }
        S[l] = __fadd_rn(__fadd_rn(__fadd_rn(t[0], t[1]), __fadd_rn(t[2], t[3])),
                         __fadd_rn(__fadd_rn(t[4], t[5]), __fadd_rn(t[6], t[7])));
    }
    float u[8];
#pragma unroll
    for (int i = 0; i < 8; ++i) u[i] = __fadd_rn(S[i], S[i + 8]);
    float v4[4];
#pragma unroll
    for (int i = 0; i < 4; ++i) v4[i] = __fadd_rn(u[i], u[i + 4]);
    return __fadd_rn(__fadd_rn(v4[0], v4[2]), __fadd_rn(v4[1], v4[3]));
}

__device__ __forceinline__ float np_sum256_sq(const float* __restrict__ p, int stride) {
    return __fadd_rn(np_half_sq(p, stride), np_half_sq(p + 128 * stride, stride));
}

__global__ __launch_bounds__(256) void e2_kernel(const float* __restrict__ emb,
                                                 float* __restrict__ e2) {
    int k = blockIdx.x * 256 + threadIdx.x;
    if (k < KCB) e2[k] = np_sum256_sq(emb + k * DIM, 1);
}

__global__ __launch_bounds__(256) void z2_kernel(const float* __restrict__ z,
                                                 float* __restrict__ z2,
                                                 unsigned long long* __restrict__ cand) {
    int n = blockIdx.x * 256 + threadIdx.x;
    z2[n] = np_sum256_sq(z + z_base(n), 1024);
    cand[n] = 0x7FFFFFFFFFFFFFFFULL;   // init for atomicMin (re-poisoned each call)
}

__device__ __forceinline__ unsigned long long pack_vi(float v, int i) {
    unsigned int u = __float_as_uint(v);
    unsigned int key = (u & 0x80000000u) ? ~u : u;   // monotone float->uint (finite)
    return ((unsigned long long)key << 32) | (unsigned int)i;
}

// smem: zs [0..4096) as [dd][128]; es [4096..4096+32*132) as [dd][132]
// (stride 132 keeps 16B alignment; staging writes 4-way max).
// After compute, [0..2048) aliased redv, [2048..4096) redi.
#define SMEM_FLOATS (4096 + 32 * 132)

#define FMA_ROW(i, zv)                                      \
    acc[i][0] = __builtin_fmaf(zv, eb0.x, acc[i][0]);       \
    acc[i][1] = __builtin_fmaf(zv, eb0.y, acc[i][1]);       \
    acc[i][2] = __builtin_fmaf(zv, eb0.z, acc[i][2]);       \
    acc[i][3] = __builtin_fmaf(zv, eb0.w, acc[i][3]);       \
    acc[i][4] = __builtin_fmaf(zv, eb1.x, acc[i][4]);       \
    acc[i][5] = __builtin_fmaf(zv, eb1.y, acc[i][5]);       \
    acc[i][6] = __builtin_fmaf(zv, eb1.z, acc[i][6]);       \
    acc[i][7] = __builtin_fmaf(zv, eb1.w, acc[i][7]);

__global__ __launch_bounds__(256) void dist_argmin_kernel(
    const float* __restrict__ z, const float* __restrict__ emb,
    const float* __restrict__ z2w, const float* __restrict__ e2w,
    unsigned long long* __restrict__ cand)
{
    __shared__ __align__(16) float smem[SMEM_FLOATS];
    float* zs = smem;            // [dd][128]
    float* es = smem + 4096;     // [dd][132]

    const int tid = threadIdx.x;
    const int tx = tid & 15;
    const int ty = tid >> 4;
    const int pt = blockIdx.x & 255;
    const int split = blockIdx.x >> 8;
    const int n0 = pt << 7;                 // 128 points per tile
    const int kbase = split << 8;           // 256 k per split

    const int zb = z_base(n0);

    float z2r[8];
#pragma unroll
    for (int i = 0; i < 8; ++i)
        z2r[i] = z2w[n0 + (i >> 2) * 64 + 4 * ty + (i & 3)];

    float bv[8];
    int   bi[8];
#pragma unroll
    for (int i = 0; i < 8; ++i) { bv[i] = __builtin_huge_valf(); bi[i] = 0; }

    // staging thread mapping
    const int sp2 = (tid & 63) * 2;         // point pair for z staging
    const int zd0 = tid >> 6;               // 0..3
    const int edd2 = (tid & 15) * 2;        // d pair for e staging
    const int ekb  = tid >> 4;              // 0..15

    for (int kt = 0; kt < 2; ++kt) {
        const int k0 = kbase + kt * BK;
        float acc[8][8];
#pragma unroll
        for (int i = 0; i < 8; ++i)
#pragma unroll
            for (int j = 0; j < 8; ++j) acc[i][j] = 0.0f;

        for (int dt = 0; dt < DIM / DT; ++dt) {
            const int dbase = dt * DT;
            __syncthreads();                // previous tile fully consumed
            // load-then-store per pair to keep live ranges short
#pragma unroll
            for (int rr = 0; rr < 8; ++rr) {
                int dd = zd0 + 4 * rr;
                float2 v = *(const float2*)(z + zb + ((dbase + dd) << 10) + sp2);
                *(float2*)(zs + dd * 128 + sp2) = v;
            }
#pragma unroll
            for (int rr = 0; rr < 8; ++rr) {
                int kk = ekb + 16 * rr;
                float2 v = *(const float2*)(emb + (k0 + kk) * DIM + dbase + edd2);
                es[edd2 * 132 + kk] = v.x;
                es[(edd2 + 1) * 132 + kk] = v.y;
            }
            __syncthreads();
#pragma unroll
            for (int dd = 0; dd < DT; ++dd) {
                const float* zrow = zs + dd * 128;
                const float* erow = es + dd * 132;
                float4 za0 = *(const float4*)(zrow + 4 * ty);
                float4 za1 = *(const float4*)(zrow + 64 + 4 * ty);
                float4 eb0 = *(const float4*)(erow + 4 * tx);
                float4 eb1 = *(const float4*)(erow + 64 + 4 * tx);
                FMA_ROW(0, za0.x)
                FMA_ROW(1, za0.y)
                FMA_ROW(2, za0.z)
                FMA_ROW(3, za0.w)
                FMA_ROW(4, za1.x)
                FMA_ROW(5, za1.y)
                FMA_ROW(6, za1.z)
                FMA_ROW(7, za1.w)
            }
        }
        // distances exactly as ref: t1 = z2 + e2 ; d = t1 - 2*dot. k ascending.
#pragma unroll
        for (int j = 0; j < 8; ++j) {
            int k = k0 + (j >> 2) * 64 + 4 * tx + (j & 3);
            float e2v = e2w[k];
#pragma unroll
            for (int i = 0; i < 8; ++i) {
                float t1 = __fadd_rn(z2r[i], e2v);
                float dcur = __fsub_rn(t1, __fmul_rn(2.0f, acc[i][j]));
                if (dcur < bv[i]) { bv[i] = dcur; bi[i] = k; }   // strict <: first min
            }
        }
    }

    // block reduction over tx (16 threads per row), np tie-break
    __syncthreads();
    float* redv = smem;                     // [128][16]
    int*   redi = (int*)(smem + 2048);      // [128][16]
#pragma unroll
    for (int i = 0; i < 8; ++i) {
        int row = (i >> 2) * 64 + 4 * ty + (i & 3);
        redv[row * 16 + tx] = bv[i];
        redi[row * 16 + tx] = bi[i];
    }
    __syncthreads();
    if (tid < 128) {
        float v = redv[tid * 16];
        int   i = redi[tid * 16];
#pragma unroll
        for (int t = 1; t < 16; ++t) {
            float v2 = redv[tid * 16 + t];
            int   i2 = redi[tid * 16 + t];
            if (v2 < v || (v2 == v && i2 < i)) { v = v2; i = i2; }
        }
        atomicMin(&cand[n0 + tid], pack_vi(v, i));
    }
}

__global__ __launch_bounds__(256) void zq_loss_kernel(
    const float* __restrict__ z, const float* __restrict__ emb,
    const unsigned long long* __restrict__ cand, float* __restrict__ zq,
    float* __restrict__ out_idx, double* __restrict__ parts)
{
    const int n = blockIdx.x * 256 + threadIdx.x;
    const int kk = (int)(unsigned int)(cand[n] & 0xFFFFFFFFULL);
    out_idx[n] = (float)kk;
    const float* er = emb + kk * DIM;
    const int zb = z_base(n);
    double s = 0.0;
#pragma unroll 8
    for (int d = 0; d < DIM; ++d) {
        float ev = er[d];
        float zv = z[zb + (d << 10)];
        zq[zb + (d << 10)] = ev;
        float df = ev - zv;
        s = fma((double)df, (double)df, s);
    }
    for (int off = 32; off; off >>= 1) s += __shfl_down(s, off, 64);
    __shared__ double sred[4];
    if ((threadIdx.x & 63) == 0) sred[threadIdx.x >> 6] = s;
    __syncthreads();
    if (threadIdx.x == 0)
        parts[blockIdx.x] = (sred[0] + sred[1]) + (sred[2] + sred[3]);
}

__global__ __launch_bounds__(128) void loss_final_kernel(
    const double* __restrict__ parts, float* __restrict__ out_loss)
{
    int t = threadIdx.x;
    double v = parts[t];
    for (int off = 32; off; off >>= 1) v += __shfl_down(v, off, 64);
    __shared__ double w2[2];
    if ((t & 63) == 0) w2[t >> 6] = v;
    __syncthreads();
    if (t == 0)
        out_loss[0] = (float)(1.25 * ((w2[0] + w2[1]) / 8388608.0));
}

extern "C" void kernel_launch(void* const* d_in, const int* in_sizes, int n_in,
                              void* d_out, int out_size, void* d_ws, size_t ws_size,
                              hipStream_t stream) {
    const float* z   = (const float*)d_in[0];
    const float* emb = (const float*)d_in[1];
    float* out = (float*)d_out;

    // ws: z2[32768] f32 | e2[1024] f32 | cand[32768] u64 | parts[128] f64
    float* z2w = (float*)d_ws;
    float* e2w = z2w + NPTS;
    unsigned long long* cand = (unsigned long long*)((char*)d_ws + 135168);
    double* parts = (double*)((char*)d_ws + 135168 + NPTS * 8);

    e2_kernel<<<KCB / 256, 256, 0, stream>>>(emb, e2w);
    z2_kernel<<<NPTS / 256, 256, 0, stream>>>(z, z2w, cand);
    dist_argmin_kernel<<<(NPTS / BM) * NSPLIT, 256, 0, stream>>>(z, emb, z2w, e2w, cand);
    zq_loss_kernel<<<NPTS / 256, 256, 0, stream>>>(z, emb, cand, out + ZQ_OFF,
                                                   out + IDX_OFF, parts);
    loss_final_kernel<<<1, 128, 0, stream>>>(parts, out + LOSS_OFF);
}